// Round 2
// baseline (460.008 us; speedup 1.0000x reference)
//
#include <hip/hip_runtime.h>
#include <hip/hip_bf16.h>
#include <math.h>

#define NUM_CLUSTERS 16
#define HIDDEN 1024
#define BOT 128
#define NTOK 65536
#define TM 64

typedef __attribute__((ext_vector_type(8))) short bf16x8;
typedef __attribute__((ext_vector_type(4))) float f32x4;

__device__ __forceinline__ unsigned short f2bf(float x) {
  union { float f; unsigned u; } v; v.f = x;
  unsigned r = v.u + 0x7fffu + ((v.u >> 16) & 1u);
  return (unsigned short)(r >> 16);
}

__device__ __forceinline__ bf16x8 pack8(float4 a, float4 b) {
  bf16x8 r;
  r[0] = (short)f2bf(a.x); r[1] = (short)f2bf(a.y);
  r[2] = (short)f2bf(a.z); r[3] = (short)f2bf(a.w);
  r[4] = (short)f2bf(b.x); r[5] = (short)f2bf(b.y);
  r[6] = (short)f2bf(b.z); r[7] = (short)f2bf(b.w);
  return r;
}

// ---------------- prep kernels ----------------

__global__ void k_zero(int* p) {
  if (threadIdx.x < 64) p[threadIdx.x] = 0;
}

__global__ void k_hist(const int* __restrict__ ids, int* __restrict__ counts) {
  __shared__ int lh[NUM_CLUSTERS];
  if (threadIdx.x < NUM_CLUSTERS) lh[threadIdx.x] = 0;
  __syncthreads();
  int i = blockIdx.x * blockDim.x + threadIdx.x;
  int stride = gridDim.x * blockDim.x;
  for (; i < NTOK; i += stride) atomicAdd(&lh[ids[i]], 1);
  __syncthreads();
  if (threadIdx.x < NUM_CLUSTERS) atomicAdd(&counts[threadIdx.x], lh[threadIdx.x]);
}

__global__ void k_scan(const int* __restrict__ counts, int* __restrict__ offsets,
                       int* __restrict__ cursor) {
  if (threadIdx.x == 0 && blockIdx.x == 0) {
    int s = 0;
    for (int c = 0; c < NUM_CLUSTERS; ++c) {
      offsets[c] = s; cursor[c] = s; s += counts[c];
    }
    offsets[NUM_CLUSTERS] = s;
  }
}

__global__ void k_scatter(const int* __restrict__ ids, int* cursor,
                          int* __restrict__ perm) {
  __shared__ int lh[NUM_CLUSTERS], lbase[NUM_CLUSTERS];
  const int tid = threadIdx.x;
  if (tid < NUM_CLUSTERS) lh[tid] = 0;
  __syncthreads();
  const int i = blockIdx.x * 256 + tid;
  const int cc = ids[i];
  const int r = atomicAdd(&lh[cc], 1);
  __syncthreads();
  if (tid < NUM_CLUSTERS) lbase[tid] = atomicAdd(&cursor[tid], lh[tid]);
  __syncthreads();
  perm[lbase[cc] + r] = i;
}

// in: [16][R][C] f32 (row-major)  ->  out: [16][C][R] bf16 (transposed)
__global__ void k_tcvt(const float* __restrict__ in, unsigned short* __restrict__ out,
                       int R, int C) {
  const int t = blockIdx.x * 256 + threadIdx.x;
  const int per = (R * C) >> 3;   // threads per cluster
  const int rdiv = R >> 3;
  const int c = t / per;
  const int rem = t - c * per;
  const int n = rem / rdiv;
  const int r8 = (rem - n * rdiv) << 3;
  const float* src = in + ((size_t)c * R + r8) * C + n;
  unsigned short v[8];
  #pragma unroll
  for (int j = 0; j < 8; ++j) v[j] = f2bf(src[(size_t)j * C]);
  *(uint4*)(out + ((size_t)c * C + n) * R + r8) = *(const uint4*)v;
}

// ---------------- fused adapter kernel ----------------
// block: 256 threads (4 waves), TM=64 gathered tokens of one cluster.
// phase1: mid[64][128] = gelu(h*W1 + b1) via mfma 16x16x32 bf16, K=1024
// phase3: out[tok] = h[tok] + mid*W2 + b2, 16 chunks of 64 output cols

#define SA_STRIDE 40    // bf16 elems per A-row (32 + 8 pad)  -> 80 B
#define SB1_OFF   2560  // A region = 64*40 shorts
#define SM_STRIDE 136   // mid / B2 stride (128 + 8 pad) -> 272 B

__global__ __launch_bounds__(256, 4) void k_adapter(
    const float* __restrict__ h, const float* __restrict__ b1g,
    const float* __restrict__ b2g, const unsigned short* __restrict__ W1bT,
    const unsigned short* __restrict__ W2bT, const int* __restrict__ offsets,
    const int* __restrict__ perm, float* __restrict__ out) {

  __shared__ __align__(16) unsigned short sMid[TM * SM_STRIDE];    // 17408 B
  __shared__ __align__(16) unsigned short sStage[TM * SM_STRIDE];  // 17408 B
  __shared__ int sTok[TM];

  const int tid = threadIdx.x;
  const int l = tid & 63;
  const int w = tid >> 6;

  // ---- locate (cluster, tile) for this block ----
  int t = blockIdx.x;
  int c;
  bool found = false;
  for (c = 0; c < NUM_CLUSTERS; ++c) {
    int cnt = offsets[c + 1] - offsets[c];
    int nt = (cnt + TM - 1) / TM;
    if (t < nt) { found = true; break; }
    t -= nt;
  }
  if (!found) return;
  const int base = offsets[c] + t * TM;
  const int nvalid = min(TM, offsets[c + 1] - base);

  if (tid < TM) sTok[tid] = perm[base + min(tid, nvalid - 1)];

  const unsigned short* W1c = W1bT + (size_t)c * BOT * HIDDEN;   // [n=128][k=1024]
  const unsigned short* W2c = W2bT + (size_t)c * HIDDEN * BOT;   // [n=1024][b=128]

  // staging role assignments
  const int arow = tid >> 2;      // 0..63   (h row)
  const int acol8 = tid & 3;      // 0..3    (8 floats)
  const int brow = tid >> 1;      // 0..127  (W1T row)
  const int bhalf = tid & 1;      // 0..1    (16 bf16)

  __syncthreads();  // sTok ready
  const long htok = (long)sTok[arow] * HIDDEN;

  f32x4 accM[4][2];
  #pragma unroll
  for (int i = 0; i < 4; ++i)
    #pragma unroll
    for (int j = 0; j < 2; ++j) { f32x4 z = {0.f, 0.f, 0.f, 0.f}; accM[i][j] = z; }

  // ---------------- phase 1: mid = h @ W1 ----------------
  for (int ks = 0; ks < 32; ++ks) {
    const int k0 = ks * 32;
    __syncthreads();  // previous iter's fragment reads done
    // stage A: 64x32 h chunk, f32 -> bf16
    {
      const float4 v0 = *(const float4*)(h + htok + k0 + acol8 * 8);
      const float4 v1 = *(const float4*)(h + htok + k0 + acol8 * 8 + 4);
      *(bf16x8*)&sStage[arow * SA_STRIDE + acol8 * 8] = pack8(v0, v1);
    }
    // stage B1: 128 rows (n) x 32 (k) of W1T bf16
    {
      const uint4* src = (const uint4*)(W1c + (size_t)brow * HIDDEN + k0 + bhalf * 16);
      uint4 q0 = src[0], q1 = src[1];
      *(uint4*)&sStage[SB1_OFF + brow * SA_STRIDE + bhalf * 16] = q0;
      *(uint4*)&sStage[SB1_OFF + brow * SA_STRIDE + bhalf * 16 + 8] = q1;
    }
    __syncthreads();
    bf16x8 af[4], bfr[2];
    #pragma unroll
    for (int mf = 0; mf < 4; ++mf)
      af[mf] = *(const bf16x8*)&sStage[(mf * 16 + (l & 15)) * SA_STRIDE + (l >> 4) * 8];
    #pragma unroll
    for (int nf = 0; nf < 2; ++nf)
      bfr[nf] = *(const bf16x8*)&sStage[SB1_OFF + (w * 32 + nf * 16 + (l & 15)) * SA_STRIDE + (l >> 4) * 8];
    #pragma unroll
    for (int mf = 0; mf < 4; ++mf)
      #pragma unroll
      for (int nf = 0; nf < 2; ++nf)
        accM[mf][nf] = __builtin_amdgcn_mfma_f32_16x16x32_bf16(af[mf], bfr[nf], accM[mf][nf], 0, 0, 0);
  }

  // ---------------- phase 2: bias + gelu -> sMid (bf16) ----------------
  const float b1v0 = b1g[c * BOT + w * 32 + (l & 15)];
  const float b1v1 = b1g[c * BOT + w * 32 + 16 + (l & 15)];
  #pragma unroll
  for (int mf = 0; mf < 4; ++mf) {
    #pragma unroll
    for (int nf = 0; nf < 2; ++nf) {
      const float bv = nf ? b1v1 : b1v0;
      #pragma unroll
      for (int r = 0; r < 4; ++r) {
        float x = accM[mf][nf][r] + bv;
        float g = 0.5f * x * (1.0f + erff(x * 0.70710678118654752f));
        const int m = mf * 16 + (l >> 4) * 4 + r;
        const int n = w * 32 + nf * 16 + (l & 15);
        sMid[m * SM_STRIDE + n] = f2bf(g);
      }
    }
  }
  __syncthreads();  // mid complete; phase-1 sStage reads all done

  // ---------------- phase 3: out = h + mid @ W2 + b2 ----------------
  const int wr = w >> 1;   // token half (0..1) -> rows wr*32..
  const int wc = w & 1;    // col half within chunk
  const int srow = tid >> 2;  // 0..63
  const int sq = tid & 3;     // 0..3 quarters of 128 bf16 (32 shorts each)

  for (int nc = 0; nc < 16; ++nc) {
    const int n0 = nc * 64;
    // stage B2: 64 rows (n) x 128 (b) of W2T bf16 — FULL 32 shorts per thread
    {
      const uint4* src = (const uint4*)(W2c + (size_t)(n0 + srow) * BOT + sq * 32);
      uint4 q0 = src[0], q1 = src[1], q2 = src[2], q3 = src[3];
      *(uint4*)&sStage[srow * SM_STRIDE + sq * 32]      = q0;
      *(uint4*)&sStage[srow * SM_STRIDE + sq * 32 + 8]  = q1;
      *(uint4*)&sStage[srow * SM_STRIDE + sq * 32 + 16] = q2;
      *(uint4*)&sStage[srow * SM_STRIDE + sq * 32 + 24] = q3;
    }
    __syncthreads();
    f32x4 acc[2][2];
    #pragma unroll
    for (int i = 0; i < 2; ++i)
      #pragma unroll
      for (int j = 0; j < 2; ++j) { f32x4 z = {0.f, 0.f, 0.f, 0.f}; acc[i][j] = z; }
    #pragma unroll
    for (int bs = 0; bs < 4; ++bs) {
      bf16x8 af[2], bfr[2];
      #pragma unroll
      for (int mf = 0; mf < 2; ++mf)
        af[mf] = *(const bf16x8*)&sMid[(wr * 32 + mf * 16 + (l & 15)) * SM_STRIDE + bs * 32 + (l >> 4) * 8];
      #pragma unroll
      for (int nf = 0; nf < 2; ++nf)
        bfr[nf] = *(const bf16x8*)&sStage[(wc * 32 + nf * 16 + (l & 15)) * SM_STRIDE + bs * 32 + (l >> 4) * 8];
      #pragma unroll
      for (int mf = 0; mf < 2; ++mf)
        #pragma unroll
        for (int nf = 0; nf < 2; ++nf)
          acc[mf][nf] = __builtin_amdgcn_mfma_f32_16x16x32_bf16(af[mf], bfr[nf], acc[mf][nf], 0, 0, 0);
    }
    // epilogue: residual + b2, predicated scatter-store
    #pragma unroll
    for (int nf = 0; nf < 2; ++nf) {
      const int nn = n0 + wc * 32 + nf * 16 + (l & 15);
      const float b2v = b2g[c * HIDDEN + nn];
      #pragma unroll
      for (int mf = 0; mf < 2; ++mf) {
        #pragma unroll
        for (int r = 0; r < 4; ++r) {
          const int m = wr * 32 + mf * 16 + (l >> 4) * 4 + r;
          if (m < nvalid) {
            const long tk = (long)sTok[m] * HIDDEN;
            out[tk + nn] = h[tk + nn] + acc[mf][nf][r] + b2v;
          }
        }
      }
    }
    __syncthreads();  // this iter's sStage reads done before next stage
  }
}

// ---------------- launcher ----------------
extern "C" void kernel_launch(void* const* d_in, const int* in_sizes, int n_in,
                              void* d_out, int out_size, void* d_ws, size_t ws_size,
                              hipStream_t stream) {
  const float* h   = (const float*)d_in[0];
  const int*   ids = (const int*)d_in[1];
  const float* W1  = (const float*)d_in[2];
  const float* b1  = (const float*)d_in[3];
  const float* W2  = (const float*)d_in[4];
  const float* b2  = (const float*)d_in[5];
  float* out = (float*)d_out;

  char* ws = (char*)d_ws;
  int* counts  = (int*)ws;            // 16 ints
  int* cursor  = (int*)(ws + 64);     // 16 ints
  int* offsets = (int*)(ws + 128);    // 17 ints
  int* perm    = (int*)(ws + 256);    // 65536 ints, ends at 262400
  unsigned short* W1bT = (unsigned short*)(ws + 262400);               // 4 MB
  unsigned short* W2bT = W1bT + (size_t)NUM_CLUSTERS * BOT * HIDDEN;   // 4 MB

  k_zero<<<1, 64, 0, stream>>>(counts);
  k_hist<<<256, 256, 0, stream>>>(ids, counts);
  k_scan<<<1, 64, 0, stream>>>(counts, offsets, cursor);
  k_scatter<<<NTOK / 256, 256, 0, stream>>>(ids, cursor, perm);
  // W1 [16][1024][128] -> W1bT [16][128][1024]; W2 [16][128][1024] -> W2bT [16][1024][128]
  k_tcvt<<<(NUM_CLUSTERS * HIDDEN * BOT / 8) / 256, 256, 0, stream>>>(W1, W1bT, HIDDEN, BOT);
  k_tcvt<<<(NUM_CLUSTERS * HIDDEN * BOT / 8) / 256, 256, 0, stream>>>(W2, W2bT, BOT, HIDDEN);

  k_adapter<<<NTOK / TM + NUM_CLUSTERS, 256, 0, stream>>>(
      h, b1, b2, W1bT, W2bT, offsets, perm, out);
}